// Round 4
// baseline (1630.823 us; speedup 1.0000x reference)
//
#include <hip/hip_runtime.h>
#include <hip/hip_bf16.h>

// Problem constants
#define BW    4096   // B words
#define TT    30     // T timesteps
#define DIN   512    // D input dim
#define HD    1024   // H hidden
#define VCH   128    // V chars
#define G4    4096   // 4*H

typedef __attribute__((ext_vector_type(8))) __bf16 bf16x8;
typedef __attribute__((ext_vector_type(4))) float  f32x4;

__device__ __forceinline__ ushort f2bf(float f) {
    unsigned u = __float_as_uint(f);
    unsigned r = (u + 0x7fffu + ((u >> 16) & 1u)) >> 16;  // RNE
    return (ushort)r;
}
__device__ __forceinline__ float sigf(float x) { return 1.f / (1.f + __expf(-x)); }
__device__ __forceinline__ float tanhfast(float x) { return 2.f / (1.f + __expf(-2.f * x)) - 1.f; }

// ---------------- setup kernels ----------------

__global__ __launch_bounds__(256) void cvt_bf16_kernel(const float* __restrict__ in,
                                                       ushort* __restrict__ out, int n4) {
    int i = blockIdx.x * 256 + threadIdx.x;
    if (i >= n4) return;
    float4 v = ((const float4*)in)[i];
    ushort4 o;
    o.x = f2bf(v.x); o.y = f2bf(v.y); o.z = f2bf(v.z); o.w = f2bf(v.w);
    ((ushort4*)out)[i] = o;
}

__global__ __launch_bounds__(256) void init_hc_kernel(const float* __restrict__ h0,
                                                      const float* __restrict__ c0,
                                                      ushort* __restrict__ hb,
                                                      float* __restrict__ c, int n4) {
    int i = blockIdx.x * 256 + threadIdx.x;
    if (i >= n4) return;
    float4 v = ((const float4*)h0)[i];
    ushort4 o;
    o.x = f2bf(v.x); o.y = f2bf(v.y); o.z = f2bf(v.z); o.w = f2bf(v.w);
    ((ushort4*)hb)[i] = o;
    ((float4*)c)[i] = ((const float4*)c0)[i];
}

// projEmb reordered: pe4[ch][h][gate] (float4 per (ch,h))
__global__ __launch_bounds__(256) void proj_emb_kernel(const float* __restrict__ emb,
                                                       const float* __restrict__ W_ih,
                                                       const float* __restrict__ b_ih,
                                                       const float* __restrict__ b_hh,
                                                       float* __restrict__ pe) {
    __shared__ float se[8][DIN];
    const int j  = blockIdx.x * 256 + threadIdx.x;   // gate-major row 0..4095
    const int c0 = blockIdx.y * 8;
    for (int i = threadIdx.x; i < 8 * DIN; i += 256)
        se[i >> 9][i & (DIN - 1)] = emb[(size_t)c0 * DIN + i];
    __syncthreads();
    const float* wv = W_ih + (size_t)j * DIN;
    float s[8];
#pragma unroll
    for (int cc = 0; cc < 8; ++cc) s[cc] = 0.f;
    for (int k = 0; k < DIN; k += 4) {
        float4 w4 = *(const float4*)&wv[k];
#pragma unroll
        for (int cc = 0; cc < 8; ++cc)
            s[cc] += se[cc][k] * w4.x + se[cc][k+1] * w4.y + se[cc][k+2] * w4.z + se[cc][k+3] * w4.w;
    }
    const float bias = b_ih[j] + b_hh[j];
    const int g = j >> 10, h = j & 1023;
#pragma unroll
    for (int cc = 0; cc < 8; ++cc)
        pe[(((size_t)(c0 + cc) * HD + h) << 2) + g] = s[cc] + bias;
}

// ---------------- fused 256^2 8-phase GEMM + LSTM cell, 3-buf A pipeline ----
// gates = h(t-1)[4096x1024] @ W_hh^T with gate-permuted N columns:
//   block col r (0..255) -> W_hh row ((r>>4)&3)*1024 + bn*64 + ((r>>6)<<4) + (r&15)
// LDS 160 KiB: A bufs 3 x 16384 ushorts at {0,16384,32768};
//              B bufs 2 x 16384 at {49152,65536}. XOR chunk swizzle as R3.
// Cadence/iter: p0,p1 stage A(2i+2); p2,p3 B(2i+2); p4,p5 A(2i+3); p6,p7 B(2i+3)
// vmcnt(8) at p3 (drains A(2i+1),B(2i+1)) and p7 (drains A(2i+2),B(2i+2)).

#define GLDS(SRC, DST)                                                                  \
    __builtin_amdgcn_global_load_lds((const __attribute__((address_space(1))) void*)(SRC), \
        (__attribute__((address_space(3))) void*)(DST), 16, 0, 0)

#define STAGE_A(DSTOFF, SH, KOFF)                                                       \
  {                                                                                     \
    ushort* dst0 = &tiles[(DSTOFF) + (SH) * 8192 + w * 1024];                           \
    GLDS(A + aOff0 + (size_t)(SH) * 131072 + (KOFF), dst0);                             \
    GLDS(A + aOff1 + (size_t)(SH) * 131072 + (KOFF), dst0 + 512);                       \
  }

#define STAGE_B(BIDX, SH, KOFF)                                                         \
  {                                                                                     \
    ushort* dst0 = &tiles[49152 + (BIDX) * 16384 + (SH) * 8192 + w * 1024];             \
    GLDS(Bt + bOff[SH][0] + (KOFF), dst0);                                              \
    GLDS(Bt + bOff[SH][1] + (KOFF), dst0 + 512);                                        \
  }

#define PHASE(ABASE, BIDX, Q, STAGE_STMT, VM)                                           \
  {                                                                                     \
    const ushort* aT = &tiles[(ABASE) + haA * 8192];                                    \
    const ushort* bT = &tiles[49152 + (BIDX) * 16384 + haB * 8192];                     \
    if ((Q) == 0) {                                                                     \
      _Pragma("unroll")                                                                 \
      for (int n = 0; n < 4; ++n) {                                                     \
        bfr[n][0] = *(const bf16x8*)(bT + hbOff + n * 1024 + aoff0);                    \
        bfr[n][1] = *(const bf16x8*)(bT + hbOff + n * 1024 + aoff1);                    \
      }                                                                                 \
    }                                                                                   \
    bf16x8 a00 = *(const bf16x8*)(aT + (2 * (Q) + 0) * 1024 + aoff0);                   \
    bf16x8 a01 = *(const bf16x8*)(aT + (2 * (Q) + 0) * 1024 + aoff1);                   \
    bf16x8 a10 = *(const bf16x8*)(aT + (2 * (Q) + 1) * 1024 + aoff0);                   \
    bf16x8 a11 = *(const bf16x8*)(aT + (2 * (Q) + 1) * 1024 + aoff1);                   \
    STAGE_STMT;                                                                         \
    __builtin_amdgcn_s_barrier();                                                       \
    asm volatile("s_waitcnt lgkmcnt(0)" ::: "memory");                                  \
    __builtin_amdgcn_s_setprio(1);                                                      \
    _Pragma("unroll")                                                                   \
    for (int n = 0; n < 4; ++n) {                                                       \
      acc[2*(Q)+0][n] = __builtin_amdgcn_mfma_f32_16x16x32_bf16(a00, bfr[n][0], acc[2*(Q)+0][n], 0, 0, 0); \
      acc[2*(Q)+0][n] = __builtin_amdgcn_mfma_f32_16x16x32_bf16(a01, bfr[n][1], acc[2*(Q)+0][n], 0, 0, 0); \
      acc[2*(Q)+1][n] = __builtin_amdgcn_mfma_f32_16x16x32_bf16(a10, bfr[n][0], acc[2*(Q)+1][n], 0, 0, 0); \
      acc[2*(Q)+1][n] = __builtin_amdgcn_mfma_f32_16x16x32_bf16(a11, bfr[n][1], acc[2*(Q)+1][n], 0, 0, 0); \
    }                                                                                   \
    __builtin_amdgcn_s_setprio(0);                                                      \
    if (VM) asm volatile("s_waitcnt vmcnt(8)" ::: "memory");                            \
    __builtin_amdgcn_s_barrier();                                                       \
    asm volatile("" ::: "memory");                                                      \
  }

__global__ __launch_bounds__(512, 2) void gemm_cell_kernel(const ushort* __restrict__ A,
                                                           const ushort* __restrict__ Bt,
                                                           const float* __restrict__ peAll,
                                                           const int* __restrict__ x,
                                                           int t, int last,
                                                           float* __restrict__ c,
                                                           ushort* __restrict__ hbN,
                                                           float* __restrict__ hout) {
    __shared__ ushort tiles[81920];  // 160 KiB

    // XCD-bijective block swizzle (256 % 8 == 0)
    const int orig = blockIdx.x;
    const int wgid = (orig & 7) * 32 + (orig >> 3);
    const int bm = wgid >> 4, bn = wgid & 15;

    const int tid = threadIdx.x;
    const int w = tid >> 6, l = tid & 63;
    const int fr = l & 15, hi = l >> 4;
    const int haA = w >> 2;           // A half this wave reads
    const int haB = (w >> 1) & 1;     // B half this wave reads
    const int hbOff = (w & 1) * 4096; // 64-row offset within B half

    // ---- staging address precompute (inverse-swizzled global source) ----
    const int r0 = w * 16 + (l >> 3), r1 = r0 + 8;
    const int csrc = (l & 7) ^ (l >> 3);
    const size_t aOff0 = (size_t)(bm * 256 + r0) * 1024 + csrc * 8;
    const size_t aOff1 = (size_t)(bm * 256 + r1) * 1024 + csrc * 8;
    size_t bOff[2][2];
#pragma unroll
    for (int half = 0; half < 2; ++half) {
        const int ra = half * 128 + r0, rb = half * 128 + r1;
        const int na = ((ra >> 4) & 3) * 1024 + bn * 64 + ((ra >> 6) << 4) + (ra & 15);
        const int nb = ((rb >> 4) & 3) * 1024 + bn * 64 + ((rb >> 6) << 4) + (rb & 15);
        bOff[half][0] = (size_t)na * 1024 + csrc * 8;
        bOff[half][1] = (size_t)nb * 1024 + csrc * 8;
    }

    // ---- ds_read fragment offsets (swizzled) ----
    const int aoff0 = fr * 64 + ((hi) ^ (fr & 7)) * 8;      // k-sub 0
    const int aoff1 = fr * 64 + ((4 + hi) ^ (fr & 7)) * 8;  // k-sub 1

    f32x4 acc[8][4];
#pragma unroll
    for (int m = 0; m < 8; ++m)
#pragma unroll
        for (int n = 0; n < 4; ++n) acc[m][n] = 0.f;
    bf16x8 bfr[4][2];

    // ---- prologue: A0, B0, A1, B1 (order matters for vmcnt(8)) ----
    STAGE_A(0, 0, 0);      STAGE_A(0, 1, 0);        // A tile 0 -> bufA0
    STAGE_B(0, 0, 0);      STAGE_B(0, 1, 0);        // B tile 0 -> bufB0
    STAGE_A(16384, 0, 64); STAGE_A(16384, 1, 64);   // A tile 1 -> bufA1
    STAGE_B(1, 0, 64);     STAGE_B(1, 1, 64);       // B tile 1 -> bufB1
    asm volatile("s_waitcnt vmcnt(8)" ::: "memory");  // A0,B0 resident
    __builtin_amdgcn_s_barrier();
    asm volatile("" ::: "memory");

    // ---- main loop: 8 iters x 2 K-tiles (K=1024, BK=64), rotating A bufs ----
    unsigned rdA0 = 0, rdA1 = 16384, stA = 32768;
    for (int i = 0; i < 8; ++i) {
        const int kO2 = ((2 * i + 2) & 15) * 64;
        const int kO3 = ((2 * i + 3) & 15) * 64;
        PHASE(rdA0, 0, 0, STAGE_A(stA, 0, kO2), 0);
        PHASE(rdA0, 0, 1, STAGE_A(stA, 1, kO2), 0);
        PHASE(rdA0, 0, 2, STAGE_B(0, 0, kO2), 0);
        PHASE(rdA0, 0, 3, STAGE_B(0, 1, kO2), 1);
        PHASE(rdA1, 1, 0, STAGE_A(rdA0, 0, kO3), 0);
        PHASE(rdA1, 1, 1, STAGE_A(rdA0, 1, kO3), 0);
        PHASE(rdA1, 1, 2, STAGE_B(1, 0, kO3), 0);
        PHASE(rdA1, 1, 3, STAGE_B(1, 1, kO3), 1);
        const unsigned tmp = rdA0; rdA0 = stA; stA = rdA1; rdA1 = tmp;
    }
    asm volatile("s_waitcnt vmcnt(0)" ::: "memory");  // drain pending LDS writes

    // ---- fused LSTM cell epilogue (n-frag == gate) ----
    const int h_idx = bn * 64 + (w & 3) * 16 + fr;
    const int bbase = bm * 256 + (w >> 2) * 128 + (hi << 2);
    const float4* pe4 = (const float4*)peAll;
#pragma unroll
    for (int m = 0; m < 8; ++m) {
#pragma unroll
        for (int r = 0; r < 4; ++r) {
            const int b = bbase + m * 16 + r;
            const int ch = x[b * TT + t];
            const float4 pv = pe4[(size_t)ch * HD + h_idx];
            float I = sigf(acc[m][0][r] + pv.x);
            float F = sigf(acc[m][1][r] + pv.y);
            float G = tanhfast(acc[m][2][r] + pv.z);
            float O = sigf(acc[m][3][r] + pv.w);
            const size_t off = (size_t)b * HD + h_idx;
            const float cn = F * c[off] + I * G;
            const float hn = O * tanhfast(cn);
            c[off] = cn;
            hbN[off] = f2bf(hn);
            if (last) hout[off] = hn;
        }
    }
}

// ---------------- launch ----------------
extern "C" void kernel_launch(void* const* d_in, const int* in_sizes, int n_in,
                              void* d_out, int out_size, void* d_ws, size_t ws_size,
                              hipStream_t stream) {
    const int*   x    = (const int*)d_in[0];
    const float* emb  = (const float*)d_in[1];
    const float* W_ih = (const float*)d_in[2];
    const float* W_hh = (const float*)d_in[3];
    const float* b_ih = (const float*)d_in[4];
    const float* b_hh = (const float*)d_in[5];
    const float* h0   = (const float*)d_in[6];
    const float* c0   = (const float*)d_in[7];
    float* out = (float*)d_out;

    char* ws = (char*)d_ws;
    ushort* whh = (ushort*)ws;                                  //  8 MiB
    float*  pe  = (float*)(ws + (size_t)8388608);               //  2 MiB (pe4 layout)
    ushort* hb0 = (ushort*)(ws + (size_t)(8388608 + 2097152));  //  8 MiB
    ushort* hb1 = (ushort*)(ws + (size_t)(8388608 + 2097152 + 8388608));             // 8 MiB
    float*  cbuf = (float*)(ws + (size_t)(8388608 + 2097152 + 8388608 + 8388608));   // 16 MiB

    cvt_bf16_kernel<<<4096, 256, 0, stream>>>(W_hh, whh, (G4 * HD) / 4);
    proj_emb_kernel<<<dim3(16, 16), 256, 0, stream>>>(emb, W_ih, b_ih, b_hh, pe);
    init_hc_kernel<<<4096, 256, 0, stream>>>(h0, c0, hb0, cbuf, (BW * HD) / 4);

    ushort* hbuf[2] = {hb0, hb1};
    for (int t = 0; t < TT; ++t) {
        gemm_cell_kernel<<<256, 512, 0, stream>>>(
            hbuf[t & 1], whh, pe, x, t, (t == TT - 1) ? 1 : 0,
            cbuf, hbuf[(t & 1) ^ 1], out);
    }
}

// Round 6
// 1624.569 us; speedup vs baseline: 1.0038x; 1.0038x over previous
//
#include <hip/hip_runtime.h>
#include <hip/hip_bf16.h>

// Problem constants
#define BW    4096   // B words
#define TT    30     // T timesteps
#define DIN   512    // D input dim
#define HD    1024   // H hidden
#define VCH   128    // V chars
#define G4    4096   // 4*H

typedef __attribute__((ext_vector_type(8))) __bf16 bf16x8;
typedef __attribute__((ext_vector_type(4))) float  f32x4;

__device__ __forceinline__ ushort f2bf(float f) {
    unsigned u = __float_as_uint(f);
    unsigned r = (u + 0x7fffu + ((u >> 16) & 1u)) >> 16;  // RNE
    return (ushort)r;
}
__device__ __forceinline__ float sigf(float x) { return 1.f / (1.f + __expf(-x)); }
__device__ __forceinline__ float tanhfast(float x) { return 2.f / (1.f + __expf(-2.f * x)) - 1.f; }

// ---------------- setup kernels ----------------

__global__ __launch_bounds__(256) void cvt_bf16_kernel(const float* __restrict__ in,
                                                       ushort* __restrict__ out, int n4) {
    int i = blockIdx.x * 256 + threadIdx.x;
    if (i >= n4) return;
    float4 v = ((const float4*)in)[i];
    ushort4 o;
    o.x = f2bf(v.x); o.y = f2bf(v.y); o.z = f2bf(v.z); o.w = f2bf(v.w);
    ((ushort4*)out)[i] = o;
}

__global__ __launch_bounds__(256) void init_hc_kernel(const float* __restrict__ h0,
                                                      const float* __restrict__ c0,
                                                      ushort* __restrict__ hb,
                                                      float* __restrict__ c, int n4) {
    int i = blockIdx.x * 256 + threadIdx.x;
    if (i >= n4) return;
    float4 v = ((const float4*)h0)[i];
    ushort4 o;
    o.x = f2bf(v.x); o.y = f2bf(v.y); o.z = f2bf(v.z); o.w = f2bf(v.w);
    ((ushort4*)hb)[i] = o;
    ((float4*)c)[i] = ((const float4*)c0)[i];
}

// projEmb reordered: pe4[ch][h][gate] (float4 per (ch,h))
__global__ __launch_bounds__(256) void proj_emb_kernel(const float* __restrict__ emb,
                                                       const float* __restrict__ W_ih,
                                                       const float* __restrict__ b_ih,
                                                       const float* __restrict__ b_hh,
                                                       float* __restrict__ pe) {
    __shared__ float se[8][DIN];
    const int j  = blockIdx.x * 256 + threadIdx.x;   // gate-major row 0..4095
    const int c0 = blockIdx.y * 8;
    for (int i = threadIdx.x; i < 8 * DIN; i += 256)
        se[i >> 9][i & (DIN - 1)] = emb[(size_t)c0 * DIN + i];
    __syncthreads();
    const float* wv = W_ih + (size_t)j * DIN;
    float s[8];
#pragma unroll
    for (int cc = 0; cc < 8; ++cc) s[cc] = 0.f;
    for (int k = 0; k < DIN; k += 4) {
        float4 w4 = *(const float4*)&wv[k];
#pragma unroll
        for (int cc = 0; cc < 8; ++cc)
            s[cc] += se[cc][k] * w4.x + se[cc][k+1] * w4.y + se[cc][k+2] * w4.z + se[cc][k+3] * w4.w;
    }
    const float bias = b_ih[j] + b_hh[j];
    const int g = j >> 10, h = j & 1023;
#pragma unroll
    for (int cc = 0; cc < 8; ++cc)
        pe[(((size_t)(c0 + cc) * HD + h) << 2) + g] = s[cc] + bias;
}

// ---------------- fused 256^2 8-phase GEMM + LSTM cell ----------------
// gates = h(t-1)[4096x1024] @ W_hh^T with gate-permuted N columns:
//   block col r (0..255) -> W_hh row ((r>>4)&3)*1024 + bn*64 + ((r>>6)<<4) + (r&15)
// XCD bn-ownership: XCD x owns bn {2x,2x+1}; 32 blocks/XCD = 16 bm x 2 bn
// -> W_hh slice (1 MiB) L2-resident across dispatches; A-tile shared by bn-pair.
// LDS: tiles 128 KiB (2 dbuf x [A,B] x [128x64]) + xs[256]. XOR chunk swizzle.

#define GLDS(SRC, DST)                                                                  \
    __builtin_amdgcn_global_load_lds((const __attribute__((address_space(1))) void*)(SRC), \
        (__attribute__((address_space(3))) void*)(DST), 16, 0, 0)

#define STAGE2(AB, SB, SH, SKT)                                                        \
  {                                                                                    \
    ushort* dst0 = &tiles[((((SB)*2 + (AB))*2 + (SH)) * 8192) + w * 1024];             \
    const ushort *s0, *s1;                                                             \
    if ((AB) == 0) {                                                                   \
      s0 = A + aOff0 + (size_t)(SH)*131072 + (size_t)(SKT)*64;                         \
      s1 = A + aOff1 + (size_t)(SH)*131072 + (size_t)(SKT)*64;                         \
    } else {                                                                           \
      s0 = Bt + bOff[SH][0] + (size_t)(SKT)*64;                                        \
      s1 = Bt + bOff[SH][1] + (size_t)(SKT)*64;                                        \
    }                                                                                  \
    GLDS(s0, dst0);                                                                    \
    GLDS(s1, dst0 + 512);                                                              \
  }

#define PHASE(BUF, Q, AB, SB, SH, SKT, VM)                                             \
  {                                                                                    \
    const ushort* aT = &tiles[(((BUF)*2 + 0)*2 + haA) * 8192];                         \
    const ushort* bT = &tiles[(((BUF)*2 + 1)*2 + haB) * 8192];                         \
    if ((Q) == 0) {                                                                    \
      _Pragma("unroll")                                                                \
      for (int n = 0; n < 4; ++n) {                                                    \
        bfr[n][0] = *(const bf16x8*)(bT + hbOff + n*1024 + aoff0);                     \
        bfr[n][1] = *(const bf16x8*)(bT + hbOff + n*1024 + aoff1);                     \
      }                                                                                \
    }                                                                                  \
    bf16x8 a00 = *(const bf16x8*)(aT + (2*(Q)+0)*1024 + aoff0);                        \
    bf16x8 a01 = *(const bf16x8*)(aT + (2*(Q)+0)*1024 + aoff1);                        \
    bf16x8 a10 = *(const bf16x8*)(aT + (2*(Q)+1)*1024 + aoff0);                        \
    bf16x8 a11 = *(const bf16x8*)(aT + (2*(Q)+1)*1024 + aoff1);                        \
    STAGE2(AB, SB, SH, SKT);                                                           \
    __builtin_amdgcn_s_barrier();                                                      \
    asm volatile("s_waitcnt lgkmcnt(0)" ::: "memory");                                 \
    __builtin_amdgcn_s_setprio(1);                                                     \
    _Pragma("unroll")                                                                  \
    for (int n = 0; n < 4; ++n) {                                                      \
      acc[2*(Q)+0][n] = __builtin_amdgcn_mfma_f32_16x16x32_bf16(a00, bfr[n][0], acc[2*(Q)+0][n], 0, 0, 0); \
      acc[2*(Q)+0][n] = __builtin_amdgcn_mfma_f32_16x16x32_bf16(a01, bfr[n][1], acc[2*(Q)+0][n], 0, 0, 0); \
      acc[2*(Q)+1][n] = __builtin_amdgcn_mfma_f32_16x16x32_bf16(a10, bfr[n][0], acc[2*(Q)+1][n], 0, 0, 0); \
      acc[2*(Q)+1][n] = __builtin_amdgcn_mfma_f32_16x16x32_bf16(a11, bfr[n][1], acc[2*(Q)+1][n], 0, 0, 0); \
    }                                                                                  \
    __builtin_amdgcn_s_setprio(0);                                                     \
    if (VM) asm volatile("s_waitcnt vmcnt(4)" ::: "memory");                           \
    __builtin_amdgcn_s_barrier();                                                      \
    asm volatile("" ::: "memory");                                                     \
  }

__global__ __launch_bounds__(512, 2) void gemm_cell_kernel(const ushort* __restrict__ A,
                                                           const ushort* __restrict__ Bt,
                                                           const float* __restrict__ peAll,
                                                           const int* __restrict__ x,
                                                           int t, int last,
                                                           float* __restrict__ c,
                                                           ushort* __restrict__ hbN,
                                                           float* __restrict__ hout) {
    __shared__ ushort tiles[65536];  // 128 KiB: [buf][A/B][half][128*64]
    __shared__ int xs[256];          // per-block char ids for this t

    // XCD bn-ownership mapping: XCD = orig&7 owns bn {2*xcd, 2*xcd+1}
    const int orig = blockIdx.x;
    const int xcd = orig & 7, j = orig >> 3;   // j = 0..31 within XCD
    const int bm = j >> 1;
    const int bn = (xcd << 1) | (j & 1);

    const int tid = threadIdx.x;
    const int w = tid >> 6, l = tid & 63;
    const int fr = l & 15, hi = l >> 4;
    const int haA = w >> 2;           // A half this wave reads
    const int haB = (w >> 1) & 1;     // B half this wave reads
    const int hbOff = (w & 1) * 4096; // 64-row offset within B half

    // stage this block's 256 char ids (removes scattered x loads from epilogue)
    if (tid < 256) xs[tid] = x[(bm * 256 + tid) * TT + t];
    __syncthreads();

    // ---- staging address precompute (inverse-swizzled global source) ----
    const int r0 = w * 16 + (l >> 3), r1 = r0 + 8;
    const int csrc = (l & 7) ^ (l >> 3);
    const size_t aOff0 = (size_t)(bm * 256 + r0) * 1024 + csrc * 8;
    const size_t aOff1 = (size_t)(bm * 256 + r1) * 1024 + csrc * 8;
    size_t bOff[2][2];
#pragma unroll
    for (int half = 0; half < 2; ++half) {
        const int ra = half * 128 + r0, rb = half * 128 + r1;
        const int na = ((ra >> 4) & 3) * 1024 + bn * 64 + ((ra >> 6) << 4) + (ra & 15);
        const int nb = ((rb >> 4) & 3) * 1024 + bn * 64 + ((rb >> 6) << 4) + (rb & 15);
        bOff[half][0] = (size_t)na * 1024 + csrc * 8;
        bOff[half][1] = (size_t)nb * 1024 + csrc * 8;
    }

    // ---- ds_read fragment offsets (swizzled) ----
    const int aoff0 = fr * 64 + ((hi) ^ (fr & 7)) * 8;      // k-sub 0
    const int aoff1 = fr * 64 + ((4 + hi) ^ (fr & 7)) * 8;  // k-sub 1

    f32x4 acc[8][4];
#pragma unroll
    for (int m = 0; m < 8; ++m)
#pragma unroll
        for (int n = 0; n < 4; ++n) acc[m][n] = 0.f;
    bf16x8 bfr[4][2];

    // ---- prologue: A0h0,A0h1,B0h0,B0h1,B1h0,B1h1 ----
    STAGE2(0, 0, 0, 0);
    STAGE2(0, 0, 1, 0);
    STAGE2(1, 0, 0, 0);
    STAGE2(1, 0, 1, 0);
    STAGE2(1, 1, 0, 1);
    STAGE2(1, 1, 1, 1);
    asm volatile("s_waitcnt vmcnt(4)" ::: "memory");
    __builtin_amdgcn_s_barrier();
    asm volatile("" ::: "memory");

    // ---- main loop: 8 iters x 2 K-tiles (K=1024, BK=64) ----
    for (int i = 0; i < 8; ++i) {
        const int k0 = 2 * i;
        PHASE(0, 0, 0, 1, 0, k0 + 1, 0);          // stage A(2i+1)h0 -> buf1
        PHASE(0, 1, 0, 1, 1, k0 + 1, 0);          // stage A(2i+1)h1
        PHASE(0, 2, 1, 0, 0, (k0 + 2) & 15, 0);   // stage B(2i+2)h0 -> buf0
        PHASE(0, 3, 1, 0, 1, (k0 + 2) & 15, 1);   // stage B(2i+2)h1, vmcnt(4)
        PHASE(1, 0, 0, 0, 0, (k0 + 2) & 15, 0);   // stage A(2i+2)h0 -> buf0
        PHASE(1, 1, 0, 0, 1, (k0 + 2) & 15, 0);   // stage A(2i+2)h1
        PHASE(1, 2, 1, 1, 0, (k0 + 3) & 15, 0);   // stage B(2i+3)h0 -> buf1
        PHASE(1, 3, 1, 1, 1, (k0 + 3) & 15, 1);   // stage B(2i+3)h1, vmcnt(4)
    }
    asm volatile("s_waitcnt vmcnt(0)" ::: "memory");  // drain pending LDS writes

    // ---- fused LSTM cell epilogue (n-frag == gate) ----
    const int h_idx = bn * 64 + (w & 3) * 16 + fr;
    const int bloc0 = (w >> 2) * 128 + (hi << 2);
    const int bbase = bm * 256 + bloc0;
    const float4* pe4 = (const float4*)peAll;
#pragma unroll
    for (int m = 0; m < 8; ++m) {
#pragma unroll
        for (int r = 0; r < 4; ++r) {
            const int b = bbase + m * 16 + r;
            const int ch = xs[bloc0 + m * 16 + r];
            const float4 pv = pe4[(size_t)ch * HD + h_idx];
            float I = sigf(acc[m][0][r] + pv.x);
            float F = sigf(acc[m][1][r] + pv.y);
            float G = tanhfast(acc[m][2][r] + pv.z);
            float O = sigf(acc[m][3][r] + pv.w);
            const size_t off = (size_t)b * HD + h_idx;
            const float cn = F * c[off] + I * G;
            const float hn = O * tanhfast(cn);
            c[off] = cn;
            hbN[off] = f2bf(hn);
            if (last) hout[off] = hn;
        }
    }
}

// ---------------- launch ----------------
extern "C" void kernel_launch(void* const* d_in, const int* in_sizes, int n_in,
                              void* d_out, int out_size, void* d_ws, size_t ws_size,
                              hipStream_t stream) {
    const int*   x    = (const int*)d_in[0];
    const float* emb  = (const float*)d_in[1];
    const float* W_ih = (const float*)d_in[2];
    const float* W_hh = (const float*)d_in[3];
    const float* b_ih = (const float*)d_in[4];
    const float* b_hh = (const float*)d_in[5];
    const float* h0   = (const float*)d_in[6];
    const float* c0   = (const float*)d_in[7];
    float* out = (float*)d_out;

    char* ws = (char*)d_ws;
    ushort* whh = (ushort*)ws;                                  //  8 MiB
    float*  pe  = (float*)(ws + (size_t)8388608);               //  2 MiB (pe4 layout)
    ushort* hb0 = (ushort*)(ws + (size_t)(8388608 + 2097152));  //  8 MiB
    ushort* hb1 = (ushort*)(ws + (size_t)(8388608 + 2097152 + 8388608));             // 8 MiB
    float*  cbuf = (float*)(ws + (size_t)(8388608 + 2097152 + 8388608 + 8388608));   // 16 MiB

    cvt_bf16_kernel<<<4096, 256, 0, stream>>>(W_hh, whh, (G4 * HD) / 4);
    proj_emb_kernel<<<dim3(16, 16), 256, 0, stream>>>(emb, W_ih, b_ih, b_hh, pe);
    init_hc_kernel<<<4096, 256, 0, stream>>>(h0, c0, hb0, cbuf, (BW * HD) / 4);

    ushort* hbuf[2] = {hb0, hb1};
    for (int t = 0; t < TT; ++t) {
        gemm_cell_kernel<<<256, 512, 0, stream>>>(
            hbuf[t & 1], whh, pe, x, t, (t == TT - 1) ? 1 : 0,
            cbuf, hbuf[(t & 1) ^ 1], out);
    }
}